// Round 1
// baseline (352.626 us; speedup 1.0000x reference)
//
#include <hip/hip_runtime.h>
#include <hip/hip_bf16.h>

#define NPLANE 6
#define QUERY 16
#define LATENT 64

// Workspace layout (floats):
//   Cxy  @ 0      : [16][32][32] = 16384
//   Cxz  @ 16384  : [16][32][16] =  8192
//   Cyz  @ 24576  : [16][32][16] =  8192
//   Ctx  @ 32768  : [16][ 8][32] =  4096
//   Cty  @ 36864  : [16][ 8][32] =  4096
//   Ctz  @ 40960  : [16][ 8][16] =  2048
// total 43008 floats = 172 KB

__global__ __launch_bounds__(256) void conv_relu_kernel(
    const float* __restrict__ p0, const float* __restrict__ p1,
    const float* __restrict__ p2, const float* __restrict__ p3,
    const float* __restrict__ p4, const float* __restrict__ p5,
    const float* __restrict__ Wt, const float* __restrict__ bias,
    float* __restrict__ ws)
{
    const int blk   = blockIdx.x;   // 0..95
    const int plane = blk >> 4;
    const int oc    = blk & 15;

    // per-plane conv (input-res) dims and ws offsets
    const int Hs[6]    = {32, 32, 32, 8, 8, 8};
    const int Wsh[6]   = {5, 4, 4, 5, 5, 4};   // log2(width): {32,16,16,32,32,16}
    const int offs[6]  = {0, 16384, 24576, 32768, 36864, 40960};

    const float* in;
    switch (plane) {
        case 0: in = p0; break;
        case 1: in = p1; break;
        case 2: in = p2; break;
        case 3: in = p3; break;
        case 4: in = p4; break;
        default: in = p5; break;
    }
    const int H  = Hs[plane];
    const int ws_shift = Wsh[plane];
    const int Wd = 1 << ws_shift;
    const int HW = H << ws_shift;

    // stage this block's 64x3x3 weights in LDS
    __shared__ float lw[LATENT * 9];
    const float* wbase = Wt + (size_t)(plane * 16 + oc) * (LATENT * 9);
    for (int i = threadIdx.x; i < LATENT * 9; i += 256) lw[i] = wbase[i];
    __syncthreads();

    const float bv = bias[plane * 16 + oc];
    float* outp = ws + offs[plane] + oc * HW;

    for (int pos = threadIdx.x; pos < HW; pos += 256) {
        const int h = pos >> ws_shift;
        const int w = pos & (Wd - 1);
        float acc = bv;
        for (int ic = 0; ic < LATENT; ++ic) {
            const float* ip  = in + ic * HW;
            const float* lwp = lw + ic * 9;
            #pragma unroll
            for (int dh = -1; dh <= 1; ++dh) {
                const int hh = h + dh;
                if ((unsigned)hh < (unsigned)H) {
                    const float* row = ip + (hh << ws_shift);
                    #pragma unroll
                    for (int dw = -1; dw <= 1; ++dw) {
                        const int wwi = w + dw;
                        if ((unsigned)wwi < (unsigned)Wd)
                            acc += row[wwi] * lwp[(dh + 1) * 3 + (dw + 1)];
                    }
                }
            }
        }
        outp[pos] = acc > 0.0f ? acc : 0.0f;
    }
}

// voxel[t][x][y][z][q] = Cxy[q][x/2][y/2] * Cxz[q][x/2][z/2] * Cyz[q][y/2][z/2]
//                      * Ctx[q][t/2][x/2] * Cty[q][t/2][y/2] * Ctz[q][t/2][z/2]
// out flat: (((t*64 + x)*64 + y)*32 + z)*16 + q
__global__ __launch_bounds__(256) void voxel_kernel(
    const float* __restrict__ ws, float* __restrict__ out)
{
    const int x   = blockIdx.x;        // 0..63
    const int t   = blockIdx.y;        // 0..15
    const int tid = threadIdx.x;

    const int j0 = (tid & 3) << 2;     // q base: 0,4,8,12
    const int z  = (tid >> 2) & 31;    // 0..31
    const int yh = tid >> 7;           // y parity 0/1

    const int x2 = x >> 1, t2 = t >> 1, z2 = z >> 1;

    const float* Cxy = ws;             // [16][32][32]
    const float* Cxz = ws + 16384;     // [16][32][16]
    const float* Cyz = ws + 24576;     // [16][32][16]
    const float* Ctx = ws + 32768;     // [16][ 8][32]
    const float* Cty = ws + 36864;     // [16][ 8][32]
    const float* Ctz = ws + 40960;     // [16][ 8][16]

    // y-invariant per-q factor
    float hq[4];
    #pragma unroll
    for (int j = 0; j < 4; ++j) {
        const int q = j0 + j;
        hq[j] = Cxz[q * 512 + x2 * 16 + z2]
              * Ctz[q * 128 + t2 * 16 + z2]
              * Ctx[q * 256 + t2 * 32 + x2];
    }

    float* obase = out + ((size_t)((t * 64 + x) * 64 + yh)) * 512 + z * 16 + j0;

    #pragma unroll 4
    for (int y2 = 0; y2 < 32; ++y2) {
        float4 v;
        float* vp = reinterpret_cast<float*>(&v);
        #pragma unroll
        for (int j = 0; j < 4; ++j) {
            const int q = j0 + j;
            const float g = Cxy[q * 1024 + x2 * 32 + y2]
                          * Cty[q * 256 + t2 * 32 + y2]
                          * Cyz[q * 512 + y2 * 16 + z2];
            vp[j] = g * hq[j];
        }
        *reinterpret_cast<float4*>(obase + (size_t)(2 * y2) * 512) = v;
    }
}

extern "C" void kernel_launch(void* const* d_in, const int* in_sizes, int n_in,
                              void* d_out, int out_size, void* d_ws, size_t ws_size,
                              hipStream_t stream)
{
    const float* p_xy = (const float*)d_in[0];
    const float* p_xz = (const float*)d_in[1];
    const float* p_yz = (const float*)d_in[2];
    const float* p_tx = (const float*)d_in[3];
    const float* p_ty = (const float*)d_in[4];
    const float* p_tz = (const float*)d_in[5];
    const float* Wt   = (const float*)d_in[6];
    const float* bias = (const float*)d_in[7];

    float* ws  = (float*)d_ws;
    float* out = (float*)d_out;

    conv_relu_kernel<<<96, 256, 0, stream>>>(p_xy, p_xz, p_yz, p_tx, p_ty, p_tz,
                                             Wt, bias, ws);
    voxel_kernel<<<dim3(64, 16), 256, 0, stream>>>(ws, out);
}

// Round 2
// 110.896 us; speedup vs baseline: 3.1798x; 3.1798x over previous
//
#include <hip/hip_runtime.h>
#include <hip/hip_bf16.h>

#define QUERY 16
#define LATENT 64

// Workspace layout (floats):
//   Cxy  @ 0      : [16][32][32] = 16384
//   Cxz  @ 16384  : [16][32][16] =  8192
//   Cyz  @ 24576  : [16][32][16] =  8192
//   Ctx  @ 32768  : [16][ 8][32] =  4096
//   Cty  @ 36864  : [16][ 8][32] =  4096
//   Ctz  @ 40960  : [16][ 8][16] =  2048

// One block computes one (plane, oc, row-chunk): CH rows x W cols, 1 px/thread.
// Branch-free inner loop: clamped tap offsets + 0/1 mask folded into weight.
template<int H, int LOGW, int CH, int WSOFF>
__device__ __forceinline__ void conv_block(
    const float* __restrict__ in, const float* __restrict__ Wt,
    const float* __restrict__ bias, float* __restrict__ ws,
    float* lw, int plane, int oc, int chunk)
{
    constexpr int W   = 1 << LOGW;
    constexpr int HW  = H * W;
    constexpr int NPX = CH * W;

    // stage this (plane,oc)'s 64x3x3 weights into LDS
    const float* wbase = Wt + (size_t)(plane * QUERY + oc) * (LATENT * 9);
    for (int i = threadIdx.x; i < LATENT * 9; i += 256) lw[i] = wbase[i];
    __syncthreads();

    const int tid = threadIdx.x;
    if (tid < NPX) {
        const int h   = chunk * CH + (tid >> LOGW);
        const int w   = tid & (W - 1);
        const int idx = h * W + w;

        // per-thread tap offsets (clamped in-bounds) and 0/1 masks
        int   off[9];
        float msk[9];
        #pragma unroll
        for (int dh = -1; dh <= 1; ++dh) {
            #pragma unroll
            for (int dw = -1; dw <= 1; ++dw) {
                const int  k  = (dh + 1) * 3 + (dw + 1);
                const bool ok = ((unsigned)(h + dh) < (unsigned)H) &&
                                ((unsigned)(w + dw) < (unsigned)W);
                off[k] = ok ? (idx + dh * W + dw) : idx;
                msk[k] = ok ? 1.0f : 0.0f;
            }
        }

        float a0 = bias[plane * QUERY + oc], a1 = 0.0f, a2 = 0.0f;
        #pragma unroll 4
        for (int ic = 0; ic < LATENT; ++ic) {
            const float* __restrict__ slab = in + ic * HW;
            const float* __restrict__ wp   = lw + ic * 9;
            a0 += slab[off[0]] * (wp[0] * msk[0]);
            a0 += slab[off[1]] * (wp[1] * msk[1]);
            a0 += slab[off[2]] * (wp[2] * msk[2]);
            a1 += slab[off[3]] * (wp[3] * msk[3]);
            a1 += slab[off[4]] * (wp[4] * msk[4]);
            a1 += slab[off[5]] * (wp[5] * msk[5]);
            a2 += slab[off[6]] * (wp[6] * msk[6]);
            a2 += slab[off[7]] * (wp[7] * msk[7]);
            a2 += slab[off[8]] * (wp[8] * msk[8]);
        }
        const float acc = a0 + a1 + a2;
        ws[WSOFF + oc * HW + idx] = fmaxf(acc, 0.0f);
    }
}

// Block ranges:
//  [  0, 64): xy  H=32 W=32, 4 chunks of 8 rows   (oc = l>>2, chunk = l&3)
//  [ 64, 96): xz  H=32 W=16, 2 chunks of 16 rows  (oc = l>>1, chunk = l&1)
//  [ 96,128): yz  H=32 W=16, 2 chunks
//  [128,144): tx  H= 8 W=32, 1 chunk
//  [144,160): ty  H= 8 W=32, 1 chunk
//  [160,176): tz  H= 8 W=16, 1 chunk (128 active threads)
__global__ __launch_bounds__(256) void conv_relu_kernel(
    const float* __restrict__ p0, const float* __restrict__ p1,
    const float* __restrict__ p2, const float* __restrict__ p3,
    const float* __restrict__ p4, const float* __restrict__ p5,
    const float* __restrict__ Wt, const float* __restrict__ bias,
    float* __restrict__ ws)
{
    __shared__ float lw[LATENT * 9];
    const int blk = blockIdx.x;

    if (blk < 64) {
        const int l = blk;
        conv_block<32, 5, 8, 0>(p0, Wt, bias, ws, lw, 0, l >> 2, l & 3);
    } else if (blk < 96) {
        const int l = blk - 64;
        conv_block<32, 4, 16, 16384>(p1, Wt, bias, ws, lw, 1, l >> 1, l & 1);
    } else if (blk < 128) {
        const int l = blk - 96;
        conv_block<32, 4, 16, 24576>(p2, Wt, bias, ws, lw, 2, l >> 1, l & 1);
    } else if (blk < 144) {
        const int l = blk - 128;
        conv_block<8, 5, 8, 32768>(p3, Wt, bias, ws, lw, 3, l, 0);
    } else if (blk < 160) {
        const int l = blk - 144;
        conv_block<8, 5, 8, 36864>(p4, Wt, bias, ws, lw, 4, l, 0);
    } else {
        const int l = blk - 160;
        conv_block<8, 4, 8, 40960>(p5, Wt, bias, ws, lw, 5, l, 0);
    }
}

// voxel[t][x][y][z][q] = Cxy[q][x/2][y/2] * Cxz[q][x/2][z/2] * Cyz[q][y/2][z/2]
//                      * Ctx[q][t/2][x/2] * Cty[q][t/2][y/2] * Ctz[q][t/2][z/2]
// out flat: (((t*64 + x)*64 + y)*32 + z)*16 + q
__global__ __launch_bounds__(256) void voxel_kernel(
    const float* __restrict__ ws, float* __restrict__ out)
{
    const int x   = blockIdx.x;        // 0..63
    const int t   = blockIdx.y;        // 0..15
    const int tid = threadIdx.x;

    const int j0 = (tid & 3) << 2;     // q base: 0,4,8,12
    const int z  = (tid >> 2) & 31;    // 0..31
    const int yh = tid >> 7;           // y parity 0/1

    const int x2 = x >> 1, t2 = t >> 1, z2 = z >> 1;

    const float* Cxy = ws;             // [16][32][32]
    const float* Cxz = ws + 16384;     // [16][32][16]
    const float* Cyz = ws + 24576;     // [16][32][16]
    const float* Ctx = ws + 32768;     // [16][ 8][32]
    const float* Cty = ws + 36864;     // [16][ 8][32]
    const float* Ctz = ws + 40960;     // [16][ 8][16]

    // y-invariant per-q factor
    float hq[4];
    #pragma unroll
    for (int j = 0; j < 4; ++j) {
        const int q = j0 + j;
        hq[j] = Cxz[q * 512 + x2 * 16 + z2]
              * Ctz[q * 128 + t2 * 16 + z2]
              * Ctx[q * 256 + t2 * 32 + x2];
    }

    float* obase = out + ((size_t)((t * 64 + x) * 64 + yh)) * 512 + z * 16 + j0;

    #pragma unroll 4
    for (int y2 = 0; y2 < 32; ++y2) {
        float4 v;
        float* vp = reinterpret_cast<float*>(&v);
        #pragma unroll
        for (int j = 0; j < 4; ++j) {
            const int q = j0 + j;
            const float g = Cxy[q * 1024 + x2 * 32 + y2]
                          * Cty[q * 256 + t2 * 32 + y2]
                          * Cyz[q * 512 + y2 * 16 + z2];
            vp[j] = g * hq[j];
        }
        *reinterpret_cast<float4*>(obase + (size_t)(2 * y2) * 512) = v;
    }
}

extern "C" void kernel_launch(void* const* d_in, const int* in_sizes, int n_in,
                              void* d_out, int out_size, void* d_ws, size_t ws_size,
                              hipStream_t stream)
{
    const float* p_xy = (const float*)d_in[0];
    const float* p_xz = (const float*)d_in[1];
    const float* p_yz = (const float*)d_in[2];
    const float* p_tx = (const float*)d_in[3];
    const float* p_ty = (const float*)d_in[4];
    const float* p_tz = (const float*)d_in[5];
    const float* Wt   = (const float*)d_in[6];
    const float* bias = (const float*)d_in[7];

    float* ws  = (float*)d_ws;
    float* out = (float*)d_out;

    conv_relu_kernel<<<176, 256, 0, stream>>>(p_xy, p_xz, p_yz, p_tx, p_ty, p_tz,
                                              Wt, bias, ws);
    voxel_kernel<<<dim3(64, 16), 256, 0, stream>>>(ws, out);
}

// Round 3
// 82.605 us; speedup vs baseline: 4.2688x; 1.3425x over previous
//
#include <hip/hip_runtime.h>
#include <hip/hip_bf16.h>

#define QUERY 16
#define LATENT 64

// Workspace layout (floats):
//   Cxy  @ 0      : [16][32][32] = 16384
//   Cxz  @ 16384  : [16][32][16] =  8192
//   Cyz  @ 24576  : [16][32][16] =  8192
//   Ctx  @ 32768  : [16][ 8][32] =  4096
//   Cty  @ 36864  : [16][ 8][32] =  4096
//   Ctz  @ 40960  : [16][ 8][16] =  2048

// ---------------------------------------------------------------------------
// Conv: one block = (plane, oc-pair, row-chunk). Input staged in LDS with a
// zero-filled halo (8 ic per group, double-buffered), so the inner loop is
// branch-free ds_read + FMA. Weights are indexed uniformly (blockIdx-only)
// -> scalar loads -> FMA with SGPR operand.
// ---------------------------------------------------------------------------
template<int H, int Wd, int CH, int WSOFF>
__device__ __forceinline__ void conv_block(
    const float* __restrict__ in, const float* __restrict__ Wt,
    const float* __restrict__ bias, float* __restrict__ ws,
    float* __restrict__ smem, int plane, int oc0, int chunk)
{
    constexpr int PW   = Wd + 2;          // padded width
    constexpr int SLAB = (CH + 2) * PW;   // padded slab floats per ic
    constexpr int GRP  = 8;               // ic per staging group
    constexpr int BUF  = GRP * SLAB;
    constexpr int NPX  = CH * Wd;
    constexpr int HW   = H * Wd;

    const int tid = threadIdx.x;
    const int r   = tid / Wd;             // Wd is a power of two -> shift
    const int c   = tid % Wd;

    const float* __restrict__ w0 = Wt + (size_t)((plane * QUERY + oc0    ) * LATENT) * 9;
    const float* __restrict__ w1 = Wt + (size_t)((plane * QUERY + oc0 + 1) * LATENT) * 9;

    auto stage = [&](int g) {
        float* buf = smem + (g & 1) * BUF;
        const float* src = in + g * GRP * HW;
        for (int s = tid; s < BUF; s += 256) {
            const int ic  = s / SLAB;
            const int rem = s - ic * SLAB;
            const int rr  = rem / PW;
            const int cc  = rem - rr * PW;
            const int row = chunk * CH + rr - 1;
            const int col = cc - 1;
            float v = 0.0f;
            if ((unsigned)row < (unsigned)H && (unsigned)col < (unsigned)Wd)
                v = src[ic * HW + row * Wd + col];
            buf[s] = v;
        }
    };

    stage(0);

    // 3 accumulators per oc to break FP dependency chains
    float a0 = 0.f, a1 = 0.f, a2 = 0.f;
    float b0 = 0.f, b1 = 0.f, b2 = 0.f;

    for (int g = 0; g < 8; ++g) {
        __syncthreads();
        if (g < 7) stage(g + 1);
        const float* buf  = smem + (g & 1) * BUF;
        const float* base = buf + (r + 1) * PW + (c + 1);
        #pragma unroll
        for (int il = 0; il < GRP; ++il) {
            const int ic = g * GRP + il;
            const float* bp = base + il * SLAB;
            const float t0 = bp[-PW - 1], t1 = bp[-PW], t2 = bp[-PW + 1];
            const float t3 = bp[-1],      t4 = bp[0],   t5 = bp[1];
            const float t6 = bp[PW - 1],  t7 = bp[PW],  t8 = bp[PW + 1];
            const float* wa = w0 + ic * 9;
            const float* wb = w1 + ic * 9;
            a0 += t0 * wa[0] + t1 * wa[1] + t2 * wa[2];
            a1 += t3 * wa[3] + t4 * wa[4] + t5 * wa[5];
            a2 += t6 * wa[6] + t7 * wa[7] + t8 * wa[8];
            b0 += t0 * wb[0] + t1 * wb[1] + t2 * wb[2];
            b1 += t3 * wb[3] + t4 * wb[4] + t5 * wb[5];
            b2 += t6 * wb[6] + t7 * wb[7] + t8 * wb[8];
        }
    }

    if (tid < NPX) {
        const float bias0 = bias[plane * QUERY + oc0];
        const float bias1 = bias[plane * QUERY + oc0 + 1];
        const float r0 = (a0 + a1) + (a2 + bias0);
        const float r1 = (b0 + b1) + (b2 + bias1);
        ws[WSOFF + (oc0    ) * HW + chunk * NPX + tid] = fmaxf(r0, 0.0f);
        ws[WSOFF + (oc0 + 1) * HW + chunk * NPX + tid] = fmaxf(r1, 0.0f);
    }
}

// Block map (88 blocks total):
//  [ 0,32): xy  H=32 W=32 CH=8   (ocp = l>>2, chunk = l&3)
//  [32,48): xz  H=32 W=16 CH=16  (ocp = l>>1, chunk = l&1)
//  [48,64): yz  H=32 W=16 CH=16
//  [64,72): tx  H= 8 W=32 CH=8
//  [72,80): ty  H= 8 W=32 CH=8
//  [80,88): tz  H= 8 W=16 CH=8   (128 active px)
__global__ __launch_bounds__(256) void conv_relu_kernel(
    const float* __restrict__ p0, const float* __restrict__ p1,
    const float* __restrict__ p2, const float* __restrict__ p3,
    const float* __restrict__ p4, const float* __restrict__ p5,
    const float* __restrict__ Wt, const float* __restrict__ bias,
    float* __restrict__ ws)
{
    __shared__ float smem[5440];   // max: 2 bufs * 8 ic * 10*34
    const int blk = blockIdx.x;

    if (blk < 32) {
        const int l = blk;
        conv_block<32, 32, 8, 0>(p0, Wt, bias, ws, smem, 0, (l >> 2) << 1, l & 3);
    } else if (blk < 48) {
        const int l = blk - 32;
        conv_block<32, 16, 16, 16384>(p1, Wt, bias, ws, smem, 1, (l >> 1) << 1, l & 1);
    } else if (blk < 64) {
        const int l = blk - 48;
        conv_block<32, 16, 16, 24576>(p2, Wt, bias, ws, smem, 2, (l >> 1) << 1, l & 1);
    } else if (blk < 72) {
        const int l = blk - 64;
        conv_block<8, 32, 8, 32768>(p3, Wt, bias, ws, smem, 3, l << 1, 0);
    } else if (blk < 80) {
        const int l = blk - 72;
        conv_block<8, 32, 8, 36864>(p4, Wt, bias, ws, smem, 4, l << 1, 0);
    } else {
        const int l = blk - 80;
        conv_block<8, 16, 8, 40960>(p5, Wt, bias, ws, smem, 5, l << 1, 0);
    }
}

// ---------------------------------------------------------------------------
// Voxel: per block (x,t) build the half-res full product
//   F[y2][z2][q] = Cxy*Cty*Cyz*Cxz*Ctz*Ctx   (8192 floats in LDS)
// then the write phase is pure ds_read_b128 + global_store_dwordx4
// (nearest-neighbor 2x upsample = each F row written twice).
// out flat: (((t*64 + x)*64 + y)*32 + z)*16 + q
// ---------------------------------------------------------------------------
__global__ __launch_bounds__(256) void voxel_kernel(
    const float* __restrict__ ws, float* __restrict__ out)
{
    __shared__ float F[8192];   // [y2=32][z2=16][q=16]
    __shared__ float G[512];    // [y2=32][q=16]  Cxy*Cty
    __shared__ float Hh[256];   // [z2=16][q=16]  Cxz*Ctz*Ctx

    const int x   = blockIdx.x;   // 0..63
    const int t   = blockIdx.y;   // 0..15
    const int tid = threadIdx.x;
    const int x2  = x >> 1, t2 = t >> 1;

    const float* Cxy = ws;             // [16][32][32]
    const float* Cxz = ws + 16384;     // [16][32][16]
    const float* Cyz = ws + 24576;     // [16][32][16]
    const float* Ctx = ws + 32768;     // [16][ 8][32]
    const float* Cty = ws + 36864;     // [16][ 8][32]
    const float* Ctz = ws + 40960;     // [16][ 8][16]

    // G[y2*16+q] = Cxy[q][x2][y2] * Cty[q][t2][y2]
    #pragma unroll
    for (int e = tid; e < 512; e += 256) {
        const int y2 = e >> 4, q = e & 15;
        G[e] = Cxy[q * 1024 + x2 * 32 + y2] * Cty[q * 256 + t2 * 32 + y2];
    }
    // Hh[z2*16+q] = Cxz[q][x2][z2] * Ctz[q][t2][z2] * Ctx[q][t2][x2]
    {
        const int z2 = tid >> 4, q = tid & 15;
        Hh[tid] = Cxz[q * 512 + x2 * 16 + z2]
                * Ctz[q * 128 + t2 * 16 + z2]
                * Ctx[q * 256 + t2 * 32 + x2];
    }
    __syncthreads();

    // F[e] = G[y2][q] * Hh[z2][q] * Cyz[q][y2][z2]
    #pragma unroll
    for (int e = tid; e < 8192; e += 256) {
        const int q  = e & 15;
        const int z2 = (e >> 4) & 15;
        const int y2 = e >> 8;
        F[e] = G[(y2 << 4) | q] * Hh[(z2 << 4) | q]
             * Cyz[q * 512 + (y2 << 4) + z2];
    }
    __syncthreads();

    // write phase: 32 iterations of LDS b128 read + 16B coalesced store
    const int j0 = (tid & 3) << 2;      // q base
    const int z  = (tid >> 2) & 31;
    const int yh = tid >> 7;            // y parity
    const int z2 = z >> 1;

    float* obase = out + ((size_t)((t * 64 + x) * 64 + yh)) * 512 + z * 16 + j0;
    const float* Fb = F + (z2 << 4) + j0;

    #pragma unroll 8
    for (int y2 = 0; y2 < 32; ++y2) {
        const float4 v = *reinterpret_cast<const float4*>(Fb + (y2 << 8));
        *reinterpret_cast<float4*>(obase + (size_t)y2 * 1024) = v;
    }
}

extern "C" void kernel_launch(void* const* d_in, const int* in_sizes, int n_in,
                              void* d_out, int out_size, void* d_ws, size_t ws_size,
                              hipStream_t stream)
{
    const float* p_xy = (const float*)d_in[0];
    const float* p_xz = (const float*)d_in[1];
    const float* p_yz = (const float*)d_in[2];
    const float* p_tx = (const float*)d_in[3];
    const float* p_ty = (const float*)d_in[4];
    const float* p_tz = (const float*)d_in[5];
    const float* Wt   = (const float*)d_in[6];
    const float* bias = (const float*)d_in[7];

    float* ws  = (float*)d_ws;
    float* out = (float*)d_out;

    conv_relu_kernel<<<88, 256, 0, stream>>>(p_xy, p_xz, p_yz, p_tx, p_ty, p_tz,
                                             Wt, bias, ws);
    voxel_kernel<<<dim3(64, 16), 256, 0, stream>>>(ws, out);
}

// Round 4
// 62.478 us; speedup vs baseline: 5.6440x; 1.3221x over previous
//
#include <hip/hip_runtime.h>

#define QUERY 16
#define LATENT 64

typedef float f4 __attribute__((ext_vector_type(4)));

// Workspace layout (floats):
//   Cxy  @ 0      : [16][32][32] = 16384
//   Cxz  @ 16384  : [16][32][16] =  8192
//   Cyz  @ 24576  : [16][32][16] =  8192
//   Ctx  @ 32768  : [16][ 8][32] =  4096
//   Cty  @ 36864  : [16][ 8][32] =  4096
//   Ctz  @ 40960  : [16][ 8][16] =  2048

// ---------------------------------------------------------------------------
// Conv: one block = (plane, oc-pair, row-chunk). TWO stages of 32 ic each:
// stage 32 padded slabs into LDS -> barrier -> ds_read taps + FMA.
// Weights/bias are blockIdx-uniform -> scalar loads.
// ---------------------------------------------------------------------------
template<int H, int Wd, int CH, int WSOFF>
__device__ __forceinline__ void conv_block(
    const float* __restrict__ in, const float* __restrict__ Wt,
    const float* __restrict__ bias, float* __restrict__ ws,
    float* __restrict__ smem, int plane, int oc0, int chunk)
{
    constexpr int PW   = Wd + 2;
    constexpr int SLAB = (CH + 2) * PW;
    constexpr int TOT  = 32 * SLAB;       // floats staged per stage
    constexpr int NPX  = CH * Wd;
    constexpr int HW   = H * Wd;
    constexpr int LOGW = (Wd == 32) ? 5 : 4;

    const int tid = threadIdx.x;
    const int r   = (tid & (NPX - 1)) >> LOGW;
    const int c   = tid & (Wd - 1);

    const float* __restrict__ w0 = Wt + (size_t)((plane * QUERY + oc0) * LATENT) * 9;
    const float* __restrict__ w1 = w0 + LATENT * 9;

    float a0 = 0.f, a1 = 0.f, a2 = 0.f;
    float b0 = 0.f, b1 = 0.f, b2 = 0.f;

    #pragma unroll
    for (int half = 0; half < 2; ++half) {
        const float* __restrict__ src = in + half * 32 * HW;
        for (int s = tid; s < TOT; s += 256) {
            const int ic  = s / SLAB;
            const int rem = s - ic * SLAB;
            const int rr  = rem / PW;
            const int cc  = rem - rr * PW;
            const int row = chunk * CH + rr - 1;
            const int col = cc - 1;
            float v = 0.0f;
            if ((unsigned)row < (unsigned)H && (unsigned)col < (unsigned)Wd)
                v = src[ic * HW + row * Wd + col];
            smem[s] = v;
        }
        __syncthreads();

        if (tid < NPX) {
            const float* base = smem + (r + 1) * PW + (c + 1);
            const float* wa0  = w0 + half * 32 * 9;
            const float* wb0  = w1 + half * 32 * 9;
            #pragma unroll 4
            for (int il = 0; il < 32; ++il) {
                const float* bp = base + il * SLAB;
                const float t0 = bp[-PW - 1], t1 = bp[-PW], t2 = bp[-PW + 1];
                const float t3 = bp[-1],      t4 = bp[0],   t5 = bp[1];
                const float t6 = bp[PW - 1],  t7 = bp[PW],  t8 = bp[PW + 1];
                const float* wa = wa0 + il * 9;
                const float* wb = wb0 + il * 9;
                a0 += t0 * wa[0] + t1 * wa[1] + t2 * wa[2];
                a1 += t3 * wa[3] + t4 * wa[4] + t5 * wa[5];
                a2 += t6 * wa[6] + t7 * wa[7] + t8 * wa[8];
                b0 += t0 * wb[0] + t1 * wb[1] + t2 * wb[2];
                b1 += t3 * wb[3] + t4 * wb[4] + t5 * wb[5];
                b2 += t6 * wb[6] + t7 * wb[7] + t8 * wb[8];
            }
        }
        __syncthreads();
    }

    if (tid < NPX) {
        const float bias0 = bias[plane * QUERY + oc0];
        const float bias1 = bias[plane * QUERY + oc0 + 1];
        const float r0 = (a0 + a1) + (a2 + bias0);
        const float r1 = (b0 + b1) + (b2 + bias1);
        ws[WSOFF + (oc0    ) * HW + chunk * NPX + (tid & (NPX - 1))] = fmaxf(r0, 0.0f);
        ws[WSOFF + (oc0 + 1) * HW + chunk * NPX + (tid & (NPX - 1))] = fmaxf(r1, 0.0f);
    }
}

// Block map (88 blocks):
//  [ 0,32): xy  H=32 W=32 CH=8   (ocp = l>>2, chunk = l&3)
//  [32,48): xz  H=32 W=16 CH=16  (ocp = l>>1, chunk = l&1)
//  [48,64): yz  H=32 W=16 CH=16
//  [64,72): tx  H= 8 W=32 CH=8
//  [72,80): ty  H= 8 W=32 CH=8
//  [80,88): tz  H= 8 W=16 CH=8   (128 active px)
__global__ __launch_bounds__(256) void conv_relu_kernel(
    const float* __restrict__ p0, const float* __restrict__ p1,
    const float* __restrict__ p2, const float* __restrict__ p3,
    const float* __restrict__ p4, const float* __restrict__ p5,
    const float* __restrict__ Wt, const float* __restrict__ bias,
    float* __restrict__ ws)
{
    __shared__ float smem[10880];   // 32 ic * max slab 340 = 43.5 KB
    const int blk = blockIdx.x;

    if (blk < 32) {
        const int l = blk;
        conv_block<32, 32, 8, 0>(p0, Wt, bias, ws, smem, 0, (l >> 2) << 1, l & 3);
    } else if (blk < 48) {
        const int l = blk - 32;
        conv_block<32, 16, 16, 16384>(p1, Wt, bias, ws, smem, 1, (l >> 1) << 1, l & 1);
    } else if (blk < 64) {
        const int l = blk - 48;
        conv_block<32, 16, 16, 24576>(p2, Wt, bias, ws, smem, 2, (l >> 1) << 1, l & 1);
    } else if (blk < 72) {
        const int l = blk - 64;
        conv_block<8, 32, 8, 32768>(p3, Wt, bias, ws, smem, 3, l << 1, 0);
    } else if (blk < 80) {
        const int l = blk - 72;
        conv_block<8, 32, 8, 36864>(p4, Wt, bias, ws, smem, 4, l << 1, 0);
    } else {
        const int l = blk - 80;
        conv_block<8, 16, 8, 40960>(p5, Wt, bias, ws, smem, 5, l << 1, 0);
    }
}

// ---------------------------------------------------------------------------
// Voxel: one block per (x2,t2) -> 256 blocks, F built ONCE per block.
// Write loop: 1 ds_read_b128 feeds 2 nontemporal dwordx4 stores (t=2t2,2t2+1).
// out flat: (((t*64 + x)*64 + y)*32 + z)*16 + q
// ---------------------------------------------------------------------------
__global__ __launch_bounds__(512) void voxel_kernel(
    const float* __restrict__ ws, float* __restrict__ out)
{
    __shared__ float F[8192];   // [y2=32][z2=16][q=16]
    __shared__ float G[512];    // [y2=32][q=16]  Cxy*Cty
    __shared__ float Hh[256];   // [z2=16][q=16]  Cxz*Ctz*Ctx

    const int b   = blockIdx.x;     // 0..255
    const int x2  = b & 31;
    const int t2  = b >> 5;         // 0..7
    const int tid = threadIdx.x;    // 0..511

    const float* Cxy = ws;             // [16][32][32]
    const float* Cxz = ws + 16384;     // [16][32][16]
    const float* Cyz = ws + 24576;     // [16][32][16]
    const float* Ctx = ws + 32768;     // [16][ 8][32]
    const float* Cty = ws + 36864;     // [16][ 8][32]
    const float* Ctz = ws + 40960;     // [16][ 8][16]

    // G[y2*16+q] = Cxy[q][x2][y2] * Cty[q][t2*2? no: t2 half-res] -- Cty index is t2
    {
        const int y2 = tid >> 4, q = tid & 15;
        G[tid] = Cxy[q * 1024 + x2 * 32 + y2] * Cty[q * 256 + t2 * 32 + y2];
    }
    if (tid < 256) {
        const int z2 = tid >> 4, q = tid & 15;
        Hh[tid] = Cxz[q * 512 + x2 * 16 + z2]
                * Ctz[q * 128 + t2 * 16 + z2]
                * Ctx[q * 256 + t2 * 32 + x2];
    }
    __syncthreads();

    #pragma unroll
    for (int e = tid; e < 8192; e += 512) {
        const int q  = e & 15;
        const int z2 = (e >> 4) & 15;
        const int y2 = e >> 8;
        F[e] = G[(y2 << 4) | q] * Hh[(z2 << 4) | q]
             * Cyz[q * 512 + (y2 << 4) + z2];
    }
    __syncthreads();

    // column decode: tid -> (j0, z, yh, xl);  t handled x2 inside (2 stores)
    const int j0 = (tid & 3) << 2;
    const int z  = (tid >> 2) & 31;
    const int yh = (tid >> 7) & 1;
    const int xl = (tid >> 8) & 1;
    const int x  = (x2 << 1) | xl;
    const int t0_ = (t2 << 1);

    float* ob0 = out + ((((size_t)(t0_ * 64 + x)) * 64 + yh) * 32 + z) * 16 + j0;
    float* ob1 = ob0 + (size_t)64 * 64 * 32 * 16;   // t+1
    const float* Fb = F + ((z >> 1) << 4) + j0;

    #pragma unroll 8
    for (int y2 = 0; y2 < 32; ++y2) {
        const f4 v = *reinterpret_cast<const f4*>(Fb + (y2 << 8));
        __builtin_nontemporal_store(v, reinterpret_cast<f4*>(ob0 + (size_t)y2 * 1024));
        __builtin_nontemporal_store(v, reinterpret_cast<f4*>(ob1 + (size_t)y2 * 1024));
    }
}

extern "C" void kernel_launch(void* const* d_in, const int* in_sizes, int n_in,
                              void* d_out, int out_size, void* d_ws, size_t ws_size,
                              hipStream_t stream)
{
    const float* p_xy = (const float*)d_in[0];
    const float* p_xz = (const float*)d_in[1];
    const float* p_yz = (const float*)d_in[2];
    const float* p_tx = (const float*)d_in[3];
    const float* p_ty = (const float*)d_in[4];
    const float* p_tz = (const float*)d_in[5];
    const float* Wt   = (const float*)d_in[6];
    const float* bias = (const float*)d_in[7];

    float* ws  = (float*)d_ws;
    float* out = (float*)d_out;

    conv_relu_kernel<<<88, 256, 0, stream>>>(p_xy, p_xz, p_yz, p_tx, p_ty, p_tz,
                                             Wt, bias, ws);
    voxel_kernel<<<256, 512, 0, stream>>>(ws, out);
}